// Round 8
// baseline (161.727 us; speedup 1.0000x reference)
//
#include <hip/hip_runtime.h>

#define B_DIM 2
#define H_DIM 16
#define S_DIM 2048
#define D_DIM 64

constexpr int QB = 64;             // q rows per block (4 waves x 16)
constexpr int KB = 64;             // keys per tile
constexpr int NT = S_DIM / KB;     // 32 key tiles
constexpr float CL2E = 0.18033688011112042f;  // (1/sqrt(64)) * log2(e)

typedef __attribute__((ext_vector_type(8))) short short8;   // 8 bf16
typedef __attribute__((ext_vector_type(4))) float f32x4;
typedef __attribute__((ext_vector_type(2))) unsigned uint2v;

__device__ __forceinline__ unsigned pkbf(float lo, float hi) {
  unsigned r;
  asm("v_cvt_pk_bf16_f32 %0, %1, %2" : "=v"(r) : "v"(lo), "v"(hi));
  return r;
}

__device__ __forceinline__ float fexp2(float x) {
  float r;
  asm("v_exp_f32 %0, %1" : "=v"(r) : "v"(x));
  return r;
}

// drain LDS ops (cross-wave visibility) but NOT vmcnt — prefetch global
// loads stay in flight across the barrier (T14).
__device__ __forceinline__ void barrier_lds() {
  asm volatile("s_waitcnt lgkmcnt(0)" ::: "memory");
  __builtin_amdgcn_s_barrier();
  asm volatile("" ::: "memory");
}

__global__ __launch_bounds__(256, 4)
void sdpa_kernel(const float* __restrict__ Qp, const float* __restrict__ Kp,
                 const float* __restrict__ Vp, const int* __restrict__ maskp,
                 float* __restrict__ ctx, float* __restrict__ attn)
{
  __shared__ __align__(16) unsigned short sK[2][KB * 64];   // [buf][key][d] bf16, swizzled, col-masked
  __shared__ __align__(16) unsigned short sV[2][64 * KB];   // [buf][d][key] bf16, swizzled
  __shared__ __align__(16) unsigned short sP[4][16 * 64];   // per-wave P [q16][key] bf16, swizzled

  const int tid  = threadIdx.x;
  const int wave = tid >> 6;
  const int lane = tid & 63;
  const int c = lane & 15;      // fragment col (q within 16)
  const int g = lane >> 4;      // fragment key-subgroup

  // XCD-aware bijective swizzle (1024 % 8 == 0): consecutive bids (same bh)
  // stay on one XCD's L2.
  const int bid = (blockIdx.x & 7) * 128 + (blockIdx.x >> 3);
  const int bh = bid >> 5;            // 32 q-tiles per (b,h)
  const int qt = bid & 31;
  const int q0 = qt * QB + wave * 16; // this wave's 16 q rows
  const size_t bhS = (size_t)bh * S_DIM;

  // staging coords
  const int key = tid >> 2;               // K: 0..63
  const int dq  = (tid & 3) << 4;         // K: 0,16,32,48
  const int kp  = (tid & 31) << 1;        // V: even key 0..62
  const int dq8 = (tid >> 5) << 3;        // V: d octet 0..56

  // ---- Q fragments (B-operand): col=q=lane&15, k = kk*32 + g*8 + j ----
  short8 qf[2];
  #pragma unroll
  for (int kk = 0; kk < 2; ++kk) {
    const float* src = Qp + (bhS + (size_t)(q0 + c)) * D_DIM + kk*32 + g*8;
    float4 a = ((const float4*)src)[0];
    float4 b = ((const float4*)src)[1];
    union { unsigned u[4]; short8 s; } w;
    w.u[0] = pkbf(a.x, a.y); w.u[1] = pkbf(a.z, a.w);
    w.u[2] = pkbf(b.x, b.y); w.u[3] = pkbf(b.z, b.w);
    qf[kk] = w.s;
  }

  // row(q)-mask * scale * log2e
  const float rvS = maskp[bhS + q0 + c] ? CL2E : 0.0f;

  // prefetch registers
  float4 kr0, kr1, kr2, kr3;
  float4 vA0, vA1, vB0, vB1;
  unsigned kmr;                 // col-mask for this thread's staged K row

  auto load_k = [&](int kt_) {
    const float* s = Kp + (bhS + (size_t)(kt_ * KB + key)) * D_DIM + dq;
    kr0 = ((const float4*)s)[0]; kr1 = ((const float4*)s)[1];
    kr2 = ((const float4*)s)[2]; kr3 = ((const float4*)s)[3];
    kmr = maskp[bhS + kt_ * KB + key] ? 0xFFFFFFFFu : 0u;
  };
  auto load_v = [&](int kt_) {
    const float* s0 = Vp + (bhS + (size_t)(kt_ * KB + kp)) * D_DIM + dq8;
    vA0 = ((const float4*)s0)[0]; vA1 = ((const float4*)s0)[1];
    vB0 = ((const float4*)(s0 + D_DIM))[0]; vB1 = ((const float4*)(s0 + D_DIM))[1];
  };
  // col-masked K staging: masked key rows stored as exact zeros -> sacc==0
  // -> p = exp2(0 + Lm) = 1/sum, exactly the reference's value.
  auto write_k = [&](int buf) {
    union { unsigned u[4]; short8 s; } w0, w1;
    w0.u[0] = pkbf(kr0.x, kr0.y) & kmr; w0.u[1] = pkbf(kr0.z, kr0.w) & kmr;
    w0.u[2] = pkbf(kr1.x, kr1.y) & kmr; w0.u[3] = pkbf(kr1.z, kr1.w) & kmr;
    w1.u[0] = pkbf(kr2.x, kr2.y) & kmr; w1.u[1] = pkbf(kr2.z, kr2.w) & kmr;
    w1.u[2] = pkbf(kr3.x, kr3.y) & kmr; w1.u[3] = pkbf(kr3.z, kr3.w) & kmr;
    const int sw = (key & 7) << 3;
    *(short8*)&sK[buf][key * 64 + (dq ^ sw)]       = w0.s;
    *(short8*)&sK[buf][key * 64 + ((dq + 8) ^ sw)] = w1.s;
  };
  auto write_v = [&](int buf) {
    float fa[8], fb[8];
    *(float4*)&fa[0] = vA0; *(float4*)&fa[4] = vA1;
    *(float4*)&fb[0] = vB0; *(float4*)&fb[4] = vB1;
    #pragma unroll
    for (int e = 0; e < 8; ++e) {
      const int d = dq8 + e;
      *(unsigned*)&sV[buf][d * KB + (kp ^ ((d & 7) << 3))] = pkbf(fa[e], fb[e]);
    }
  };

  float lsum = 0.0f;

  // ================= pass 1: row sums of exp(s) =================
  load_k(0);
  for (int kt = 0; kt < NT; ++kt) {
    const int cur = kt & 1;
    write_k(cur);
    if (kt + 1 < NT) load_k(kt + 1);
    barrier_lds();

    short8 kf[4][2];
    #pragma unroll
    for (int n = 0; n < 4; ++n) {
      const int k2 = n*16 + c;
      const int sw = (c & 7) << 3;
      #pragma unroll
      for (int kk = 0; kk < 2; ++kk)
        kf[n][kk] = *(const short8*)&sK[cur][k2*64 + ((kk*32 + g*8) ^ sw)];
    }

    f32x4 sacc[4];
    #pragma unroll
    for (int n = 0; n < 4; ++n) sacc[n] = 0.0f;
    __builtin_amdgcn_s_setprio(1);
    #pragma unroll
    for (int n = 0; n < 4; ++n)
      #pragma unroll
      for (int kk = 0; kk < 2; ++kk)
        sacc[n] = __builtin_amdgcn_mfma_f32_16x16x32_bf16(kf[n][kk], qf[kk], sacc[n], 0, 0, 0);
    __builtin_amdgcn_s_setprio(0);

    #pragma unroll
    for (int n = 0; n < 4; ++n)
      #pragma unroll
      for (int e = 0; e < 4; ++e)
        lsum += fexp2(sacc[n][e] * rvS);
  }

  // reduce over the 4 key-subgroups -> log2 of reciprocal row sum
  float Lm;
  {
    float v = lsum;
    v += __shfl_xor(v, 16);
    v += __shfl_xor(v, 32);
    Lm = -__log2f(v);
  }

  // ================= pass 2: recompute, write attn, PV =================
  f32x4 oacc[4];
  #pragma unroll
  for (int n = 0; n < 4; ++n) oacc[n] = 0.0f;

  unsigned short* const myP = sP[wave];
  const int rh  = lane >> 4;
  const int c16 = lane & 15;
  float* const abase = attn + (bhS + (size_t)q0) * S_DIM;

  // attn copy-out from sP: 4 rows x 256B = 1KB contiguous per store
  auto copyout = [&](int kt_) {
    float* const at = abase + kt_*KB;
    #pragma unroll
    for (int j = 0; j < 4; ++j) {
      const int rr = j*4 + rh;                    // 0..15
      const int p8 = (c16 >> 1) ^ (rr & 7);
      uint2v u = *(const uint2v*)&myP[rr*64 + p8*8 + (c16 & 1)*4];
      union { unsigned iu; float f; } t0, t1, t2, t3;
      t0.iu = u.x << 16; t1.iu = u.x & 0xFFFF0000u;
      t2.iu = u.y << 16; t3.iu = u.y & 0xFFFF0000u;
      f32x4 o; o[0] = t0.f; o[1] = t1.f; o[2] = t2.f; o[3] = t3.f;
      __builtin_nontemporal_store(o, (f32x4*)(at + (size_t)rr * S_DIM + c16*4));
    }
  };

  load_k(0); load_v(0);
  for (int kt = 0; kt < NT; ++kt) {
    const int cur = kt & 1;
    write_k(cur);
    write_v(cur);
    if (kt + 1 < NT) { load_k(kt + 1); load_v(kt + 1); }
    barrier_lds();

    short8 kf[4][2];
    #pragma unroll
    for (int n = 0; n < 4; ++n) {
      const int k2 = n*16 + c;
      const int sw = (c & 7) << 3;
      #pragma unroll
      for (int kk = 0; kk < 2; ++kk)
        kf[n][kk] = *(const short8*)&sK[cur][k2*64 + ((kk*32 + g*8) ^ sw)];
    }

    f32x4 sacc[4];
    #pragma unroll
    for (int n = 0; n < 4; ++n) sacc[n] = 0.0f;
    __builtin_amdgcn_s_setprio(1);
    #pragma unroll
    for (int n = 0; n < 4; ++n)
      #pragma unroll
      for (int kk = 0; kk < 2; ++kk)
        sacc[n] = __builtin_amdgcn_mfma_f32_16x16x32_bf16(kf[n][kk], qf[kk], sacc[n], 0, 0, 0);
    __builtin_amdgcn_s_setprio(0);

    // p = exp2(s*rvS + Lm) -> bf16 into wave-private sP (swizzled)
    #pragma unroll
    for (int n = 0; n < 4; ++n) {
      f32x4 pv;
      #pragma unroll
      for (int e = 0; e < 4; ++e)
        pv[e] = fexp2(__builtin_fmaf(sacc[n][e], rvS, Lm));
      const int swk = (n*16 + g*4) ^ ((c & 7) << 3);
      uint2v pr; pr.x = pkbf(pv[0], pv[1]); pr.y = pkbf(pv[2], pv[3]);
      *(uint2v*)&myP[c*64 + swk] = pr;
    }

    // PV: A = P[q][key] from sP, B = V[key][d] from transposed sV
    short8 pf[2];
    #pragma unroll
    for (int kk = 0; kk < 2; ++kk)
      pf[kk] = *(const short8*)&myP[c*64 + ((kk*32 + g*8) ^ ((c & 7) << 3))];
    __builtin_amdgcn_s_setprio(1);
    #pragma unroll
    for (int n = 0; n < 4; ++n) {
      const int d = n*16 + c;
      const int sw = (d & 7) << 3;
      #pragma unroll
      for (int kk = 0; kk < 2; ++kk) {
        short8 vf = *(const short8*)&sV[cur][d*KB + ((kk*32 + g*8) ^ sw)];
        oacc[n] = __builtin_amdgcn_mfma_f32_16x16x32_bf16(pf[kk], vf, oacc[n], 0, 0, 0);
      }
    }
    __builtin_amdgcn_s_setprio(0);

    // copy-out this tile's attn: stores drain under next tile's staging,
    // barrier (no vmcnt drain) and QK compute
    copyout(kt);
  }

  // context write (row q = g*4 + e, col d = n*16 + c)
  #pragma unroll
  for (int n = 0; n < 4; ++n)
    #pragma unroll
    for (int e = 0; e < 4; ++e) {
      const int rl = g*4 + e;
      ctx[(bhS + (size_t)(q0 + rl)) * D_DIM + (size_t)(n*16 + c)] = oacc[n][e];
    }
}

extern "C" void kernel_launch(void* const* d_in, const int* in_sizes, int n_in,
                              void* d_out, int out_size, void* d_ws, size_t ws_size,
                              hipStream_t stream) {
  const float* Q = (const float*)d_in[0];
  const float* K = (const float*)d_in[1];
  const float* V = (const float*)d_in[2];
  const int*   M = (const int*)d_in[3];
  float* ctx  = (float*)d_out;
  float* attn = ctx + (size_t)B_DIM * H_DIM * S_DIM * D_DIM;
  dim3 grid(B_DIM * H_DIM * (S_DIM / QB));   // 1024 blocks
  sdpa_kernel<<<grid, 256, 0, stream>>>(Q, K, V, M, ctx, attn);
}